// Round 6
// baseline (367.428 us; speedup 1.0000x reference)
//
#include <hip/hip_runtime.h>
#include <stdint.h>

// Problem constants: T_OBS=8, T_PRE=12, B=524288, IN=2, E=16, H=8
#define T_OBS 8
#define T_PRE 12
#define BATCH 524288
#define NWPH  192   // dwords per phase weight block in ws

typedef _Float16 f16x2 __attribute__((ext_vector_type(2)));
typedef unsigned short u16x2 __attribute__((ext_vector_type(2)));

// __builtin_amdgcn_cvt_pkrtz returns __fp16x2; bit-cast to our f16x2.
__device__ __forceinline__ f16x2 pkrtz(float a, float b) {
    return __builtin_bit_cast(f16x2, __builtin_amdgcn_cvt_pkrtz(a, b));
}

__device__ __forceinline__ f16x2 h2(float v) {
    f16x2 r; r.x = (_Float16)v; r.y = (_Float16)v; return r;
}

// Packed f16 reciprocal: exponent-flip seed (rel err <= 12.5% for normal d>0)
// + 2 Newton iterations -> rel err ~2.4e-4 (f16 eps floor ~5e-4).
__device__ __forceinline__ f16x2 pk_rcp(f16x2 d) {
    u16x2 db = __builtin_bit_cast(u16x2, d);
    u16x2 rb;
    rb.x = (unsigned short)(0x7800u - db.x);
    rb.y = (unsigned short)(0x7800u - db.y);
    f16x2 r = __builtin_bit_cast(f16x2, rb);
    f16x2 two = h2(2.0f);
    r = r * (two - d * r);
    r = r * (two - d * r);
    return r;
}

// tanh via exact Pade(7,6) from the tanh continued fraction
//   t = x(10395 + 1260 x^2 + 21 x^4) / (10395 + 4725 x^2 + 210 x^4 + x^6)
// coefficients divided by 64 so all intermediates stay in f16 range.
// Input clamped to [-4.5, 4.5]; max abs error ~7.4e-4 (tail) + f16 eval noise.
__device__ __forceinline__ f16x2 tanh_pk(f16x2 x) {
    x = __builtin_elementwise_max(x, h2(-4.5f));
    x = __builtin_elementwise_min(x, h2( 4.5f));
    f16x2 x2  = x * x;
    f16x2 num = ((h2(0.328125f)  * x2 + h2(19.6875f)) * x2 + h2(162.421875f)) * x;
    f16x2 den = ((h2(0.015625f)  * x2 + h2(3.28125f)) * x2 + h2(73.828125f)) * x2
                + h2(162.421875f);
    return num * pk_rcp(den);
}

// sigmoid(2*xh) = 0.5 + 0.5*tanh(xh) — i/f/o weight rows are prescaled by 0.5.
__device__ __forceinline__ f16x2 sig_pk(f16x2 xh) {
    f16x2 t = tanh_pk(xh);
    return t * h2(0.5f) + h2(0.5f);
}

// ---------------------------------------------------------------------------
// Weight prep: fold embedding into LSTM input weights; prescale sigmoid rows
// (i,f,o) by 0.5 so sigmoid(x) = 0.5+0.5*tanh(x/2) needs no runtime scaling;
// g rows unscaled. Pack to f16 pairs for v_dot2_f32_f16.
// ws layout per phase (obs at +0, pre at +NWPH), dwords:
//   [0..31]   bias f32 (prescaled)   rows: i 0-7, f 8-15, g 16-23, o 24-31
//   [32..63]  wx  f16x2 per row (prescaled)
//   [64..191] wh  f16x2 [row*4+j] = (wh[2j],wh[2j+1]) (prescaled)
// ---------------------------------------------------------------------------
__global__ void prep_weights(const float* __restrict__ W_in,
                             const float* __restrict__ b_in,
                             const float* __restrict__ W_ih_obs,
                             const float* __restrict__ W_hh_obs,
                             const float* __restrict__ b_ih_obs,
                             const float* __restrict__ b_hh_obs,
                             const float* __restrict__ W_ih_pre,
                             const float* __restrict__ W_hh_pre,
                             const float* __restrict__ b_ih_pre,
                             const float* __restrict__ b_hh_pre,
                             float* __restrict__ ws) {
    int t = threadIdx.x;            // 0..63; one wave
    int g = t & 31;                 // row index
    bool pre = t >= 32;
    const float* W_ih = pre ? W_ih_pre : W_ih_obs;
    const float* W_hh = pre ? W_hh_pre : W_hh_obs;
    const float* b_ih = pre ? b_ih_pre : b_ih_obs;
    const float* b_hh = pre ? b_hh_pre : b_hh_obs;
    float* base = ws + (pre ? NWPH : 0);

    float scale = (g >= 16 && g < 24) ? 1.0f : 0.5f;   // tanh rows raw, sigmoid rows half

    float wx0 = 0.f, wx1 = 0.f;
    float bb = b_ih[g] + b_hh[g];
    #pragma unroll
    for (int e = 0; e < 16; e++) {
        float wie = W_ih[g * 16 + e];
        wx0 += wie * W_in[e * 2 + 0];
        wx1 += wie * W_in[e * 2 + 1];
        bb  += wie * b_in[e];
    }
    base[g] = bb * scale;
    f16x2* wxp = (f16x2*)(base + 32);
    f16x2 vx; vx.x = (_Float16)(wx0 * scale); vx.y = (_Float16)(wx1 * scale);
    wxp[g] = vx;
    f16x2* whp = (f16x2*)(base + 64);
    #pragma unroll
    for (int j = 0; j < 4; j++) {
        f16x2 vh;
        vh.x = (_Float16)(W_hh[g * 8 + 2 * j    ] * scale);
        vh.y = (_Float16)(W_hh[g * 8 + 2 * j + 1] * scale);
        whp[g * 4 + j] = vh;
    }
}

// ---------------------------------------------------------------------------
// LSTM step: gates via fdot2 (f32 acc), activations via packed-f16 Pade.
// ---------------------------------------------------------------------------
__device__ __forceinline__ void lstm_step(f16x2 xp,
                                          const float bias[32],
                                          const f16x2 wx[32],
                                          const f16x2 wh[128],
                                          f16x2 hp[4], float c[8]) {
    float gI[8], gF[8], gG[8], gO[8];
    #pragma unroll
    for (int u = 0; u < 8; u++) {
        float gi = __builtin_amdgcn_fdot2(wx[u     ], xp, bias[u     ], false);
        float gf = __builtin_amdgcn_fdot2(wx[u +  8], xp, bias[u +  8], false);
        float gg = __builtin_amdgcn_fdot2(wx[u + 16], xp, bias[u + 16], false);
        float go = __builtin_amdgcn_fdot2(wx[u + 24], xp, bias[u + 24], false);
        #pragma unroll
        for (int j = 0; j < 4; j++) {
            gi = __builtin_amdgcn_fdot2(wh[(u     ) * 4 + j], hp[j], gi, false);
            gf = __builtin_amdgcn_fdot2(wh[(u +  8) * 4 + j], hp[j], gf, false);
            gg = __builtin_amdgcn_fdot2(wh[(u + 16) * 4 + j], hp[j], gg, false);
            go = __builtin_amdgcn_fdot2(wh[(u + 24) * 4 + j], hp[j], go, false);
        }
        gI[u] = gi; gF[u] = gf; gG[u] = gg; gO[u] = go;
    }
    // activations per unit-pair, all in packed f16
    #pragma unroll
    for (int p = 0; p < 4; p++) {
        f16x2 pi = pkrtz(gI[2*p], gI[2*p+1]);
        f16x2 pf = pkrtz(gF[2*p], gF[2*p+1]);
        f16x2 pg = pkrtz(gG[2*p], gG[2*p+1]);
        f16x2 po = pkrtz(gO[2*p], gO[2*p+1]);
        f16x2 si = sig_pk(pi);
        f16x2 sf = sig_pk(pf);
        f16x2 tg = tanh_pk(pg);
        f16x2 so = sig_pk(po);
        // c update in f32 (exact recurrence precision)
        float cn0 = (float)sf.x * c[2*p]     + (float)si.x * (float)tg.x;
        float cn1 = (float)sf.y * c[2*p + 1] + (float)si.y * (float)tg.y;
        c[2*p] = cn0; c[2*p + 1] = cn1;
        f16x2 tc = tanh_pk(pkrtz(cn0, cn1));
        hp[p] = so * tc;     // packed h, ready for next step's fdot2
    }
}

__global__ __launch_bounds__(256, 4)
void lstm_encoder(const float2* __restrict__ obs,
                  const float2* __restrict__ pre,
                  const float4* __restrict__ h0,
                  const float4* __restrict__ c0,
                  const float4* __restrict__ c0p,
                  const float* __restrict__ w,
                  float* __restrict__ out) {
    int b = blockIdx.x * blockDim.x + threadIdx.x;

    f16x2 hp[4];
    float c[8];
    {
        float4 h01 = h0[(size_t)b * 2], h02 = h0[(size_t)b * 2 + 1];
        float4 c01 = c0[(size_t)b * 2], c02 = c0[(size_t)b * 2 + 1];
        hp[0] = pkrtz(h01.x, h01.y);
        hp[1] = pkrtz(h01.z, h01.w);
        hp[2] = pkrtz(h02.x, h02.y);
        hp[3] = pkrtz(h02.z, h02.w);
        c[0] = c01.x; c[1] = c01.y; c[2] = c01.z; c[3] = c01.w;
        c[4] = c02.x; c[5] = c02.y; c[6] = c02.z; c[7] = c02.w;
    }

    // obs-phase weights
    float bias[32]; f16x2 wx[32]; f16x2 wh[128];
    {
        const f16x2* wxs = (const f16x2*)(w + 32);
        const f16x2* whs = (const f16x2*)(w + 64);
        #pragma unroll
        for (int i = 0; i < 32; i++) { bias[i] = w[i]; wx[i] = wxs[i]; }
        #pragma unroll
        for (int i = 0; i < 128; i++) wh[i] = whs[i];
    }

    #pragma unroll 1
    for (int t = 0; t < T_OBS; t++) {
        float2 xv = obs[(size_t)t * BATCH + b];
        lstm_step(pkrtz(xv.x, xv.y), bias, wx, wh, hp, c);
    }

    // c_out flat layout (transpose-then-reshape): out[j*B + b] = h[b][j]
    #pragma unroll
    for (int p = 0; p < 4; p++) {
        out[(size_t)(2*p    ) * BATCH + b] = (float)hp[p].x;
        out[(size_t)(2*p + 1) * BATCH + b] = (float)hp[p].y;
    }

    // pre phase: h carries over, c re-initialized, new weights
    {
        float4 c01 = c0p[(size_t)b * 2], c02 = c0p[(size_t)b * 2 + 1];
        c[0] = c01.x; c[1] = c01.y; c[2] = c01.z; c[3] = c01.w;
        c[4] = c02.x; c[5] = c02.y; c[6] = c02.z; c[7] = c02.w;
    }
    {
        const float* w2 = w + NWPH;
        const f16x2* wxs = (const f16x2*)(w2 + 32);
        const f16x2* whs = (const f16x2*)(w2 + 64);
        #pragma unroll
        for (int i = 0; i < 32; i++) { bias[i] = w2[i]; wx[i] = wxs[i]; }
        #pragma unroll
        for (int i = 0; i < 128; i++) wh[i] = whs[i];
    }

    #pragma unroll 1
    for (int t = 0; t < T_PRE; t++) {
        float2 xv = pre[(size_t)t * BATCH + b];
        lstm_step(pkrtz(xv.x, xv.y), bias, wx, wh, hp, c);
    }

    #pragma unroll
    for (int p = 0; p < 4; p++) {
        out[(size_t)(8 + 2*p    ) * BATCH + b] = (float)hp[p].x;
        out[(size_t)(8 + 2*p + 1) * BATCH + b] = (float)hp[p].y;
    }
}

extern "C" void kernel_launch(void* const* d_in, const int* in_sizes, int n_in,
                              void* d_out, int out_size, void* d_ws, size_t ws_size,
                              hipStream_t stream) {
    prep_weights<<<1, 64, 0, stream>>>(
        (const float*)d_in[5],  (const float*)d_in[6],
        (const float*)d_in[7],  (const float*)d_in[8],
        (const float*)d_in[9],  (const float*)d_in[10],
        (const float*)d_in[11], (const float*)d_in[12],
        (const float*)d_in[13], (const float*)d_in[14],
        (float*)d_ws);

    lstm_encoder<<<BATCH / 256, 256, 0, stream>>>(
        (const float2*)d_in[0], (const float2*)d_in[1],
        (const float4*)d_in[2], (const float4*)d_in[3], (const float4*)d_in[4],
        (const float*)d_ws, (float*)d_out);
}

// Round 7
// 230.210 us; speedup vs baseline: 1.5961x; 1.5961x over previous
//
#include <hip/hip_runtime.h>
#include <stdint.h>

// Problem constants: T_OBS=8, T_PRE=12, B=524288, IN=2, E=16, H=8
#define T_OBS 8
#define T_PRE 12
#define BATCH 524288

#define NLOG2E  (-1.4426950408889634f)   // -log2(e): sigmoid prescale
#define P2LOG2E ( 2.8853900817779268f)   // +2*log2(e): tanh prescale

typedef __fp16 half8  __attribute__((ext_vector_type(8)));
typedef float  floatx16 __attribute__((ext_vector_type(16)));
typedef unsigned int uint_t;

__device__ __forceinline__ uint_t upk(float a, float b) {
    return __builtin_bit_cast(uint_t, __builtin_amdgcn_cvt_pkrtz(a, b));
}

// ---------------------------------------------------------------------------
// Weight prep -> per-lane MFMA A-fragments for v_mfma_f32_32x32x16_f16.
// A matrix: [M=32 gate rows (i0-7,f0-7,g0-7,o0-7)] x [K=16]:
//   k=0,1   : folded input weights (W_ih @ W_in), prescaled
//   k=2..9  : W_hh row, prescaled
//   k=10    : folded bias (W_ih@b_in + b_ih + b_hh), prescaled  (B[k=10]=1.0)
//   k=11..15: 0
// Sigmoid rows (i,f,o) scaled by -log2e; tanh rows (g) by +2log2e.
// A-fragment layout: lane l holds A[m=l&31][k=(l>>5)*8 + j], j=0..7,
// packed as 4 dwords (f16 pairs). ws layout: uint[phase*256 + lane*4 + r].
// ---------------------------------------------------------------------------
__global__ void prep_weights(const float* __restrict__ W_in,
                             const float* __restrict__ b_in,
                             const float* __restrict__ W_ih_obs,
                             const float* __restrict__ W_hh_obs,
                             const float* __restrict__ b_ih_obs,
                             const float* __restrict__ b_hh_obs,
                             const float* __restrict__ W_ih_pre,
                             const float* __restrict__ W_hh_pre,
                             const float* __restrict__ b_ih_pre,
                             const float* __restrict__ b_hh_pre,
                             uint_t* __restrict__ wsu) {
    int t = threadIdx.x;            // 0..127: phase*64 + lane
    int phase = t >> 6;
    int l = t & 63;
    int m = l & 31;                 // gate row
    int kh = l >> 5;                // k-half: 0 -> k0..7, 1 -> k8..15
    const float* W_ih = phase ? W_ih_pre : W_ih_obs;
    const float* W_hh = phase ? W_hh_pre : W_hh_obs;
    const float* b_ih = phase ? b_ih_pre : b_ih_obs;
    const float* b_hh = phase ? b_hh_pre : b_hh_obs;

    float wx0 = 0.f, wx1 = 0.f;
    float bb = b_ih[m] + b_hh[m];
    #pragma unroll
    for (int e = 0; e < 16; e++) {
        float wie = W_ih[m * 16 + e];
        wx0 += wie * W_in[e * 2 + 0];
        wx1 += wie * W_in[e * 2 + 1];
        bb  += wie * b_in[e];
    }
    float s = (m >= 16 && m < 24) ? P2LOG2E : NLOG2E;

    float af[16];
    af[0] = wx0 * s;
    af[1] = wx1 * s;
    #pragma unroll
    for (int j = 0; j < 8; j++) af[2 + j] = W_hh[m * 8 + j] * s;
    af[10] = bb * s;
    #pragma unroll
    for (int k = 11; k < 16; k++) af[k] = 0.f;

    #pragma unroll
    for (int r = 0; r < 4; r++)
        wsu[phase * 256 + l * 4 + r] = upk(af[kh * 8 + 2 * r], af[kh * 8 + 2 * r + 1]);
}

// ---------------------------------------------------------------------------
// One LSTM step for 32 batch elements per wave via a single 32x32x16 MFMA.
// Lane n (n<32) owns units 0-3 of batch col n; lane n+32 owns units 4-7.
// ---------------------------------------------------------------------------
__device__ __forceinline__ void lstm_step(half8 A, uint_t xpk, bool lo,
                                          uint_t& pk0, uint_t& pk1,
                                          float c[4], float h[4],
                                          const floatx16& zacc) {
    // B fragment: col n, k rows. lower lanes k0-7 = (x0,x1,h0..h5);
    // upper lanes k8-15 = (h6,h7,1,0,...). lower pk0=(h0,h1),pk1=(h2,h3);
    // upper pk0=(h4,h5),pk1=(h6,h7). Lower needs (h4,h5) from its upper twin.
    uint_t other = (uint_t)__shfl_xor((int)pk0, 32, 64);
    uint4 bu;
    bu.x = lo ? xpk : pk1;            // k0,1 | k8,9
    bu.y = lo ? pk0 : 0x00003C00u;    // k2,3 | k10=1.0, k11=0
    bu.z = lo ? pk1 : 0u;             // k4,5 | k12,13
    bu.w = lo ? other : 0u;           // k6,7 | k14,15
    half8 B = __builtin_bit_cast(half8, bu);

    floatx16 d = __builtin_amdgcn_mfma_f32_32x32x16_f16(A, B, zacc, 0, 0, 0);

    // D rows for this lane: reg j -> i-unit, 4+j -> f, 8+j -> g, 12+j -> o
    #pragma unroll
    for (int j = 0; j < 4; j++) {
        float gi = d[j], gf = d[4 + j], gg = d[8 + j], go = d[12 + j];
        float si = __builtin_amdgcn_rcpf(1.f + __builtin_amdgcn_exp2f(gi));
        float sf = __builtin_amdgcn_rcpf(1.f + __builtin_amdgcn_exp2f(gf));
        float so = __builtin_amdgcn_rcpf(1.f + __builtin_amdgcn_exp2f(go));
        float tg = 1.f - 2.f * __builtin_amdgcn_rcpf(1.f + __builtin_amdgcn_exp2f(gg));
        float cn = sf * c[j] + si * tg;
        c[j] = cn;
        float tc = 1.f - 2.f * __builtin_amdgcn_rcpf(1.f + __builtin_amdgcn_exp2f(P2LOG2E * cn));
        h[j] = so * tc;
    }
    pk0 = upk(h[0], h[1]);
    pk1 = upk(h[2], h[3]);
}

__global__ __launch_bounds__(256, 2)
void lstm_encoder(const float2* __restrict__ obs,
                  const float2* __restrict__ pre,
                  const float4* __restrict__ h0,
                  const float4* __restrict__ c0,
                  const float4* __restrict__ c0p,
                  const uint4* __restrict__ wf,
                  float* __restrict__ out) {
    const int tid  = threadIdx.x;
    const int lane = tid & 63;
    const int wv   = tid >> 6;              // wave in block: 0..3
    const int n    = lane & 31;             // batch col within tile
    const int half = lane >> 5;             // 0: units 0-3, 1: units 4-7
    const bool lo  = (half == 0);
    const size_t nb = (size_t)blockIdx.x * 128 + wv * 32 + n;

    half8 Aobs = __builtin_bit_cast(half8, wf[lane]);
    half8 Apre = __builtin_bit_cast(half8, wf[64 + lane]);

    floatx16 zacc;
    #pragma unroll
    for (int i = 0; i < 16; i++) zacc[i] = 0.f;

    // init: this lane's 4 units of h and c
    float4 hv = h0[nb * 2 + half];
    float4 cv = c0[nb * 2 + half];
    float c[4] = {cv.x, cv.y, cv.z, cv.w};
    float h[4] = {hv.x, hv.y, hv.z, hv.w};
    uint_t pk0 = upk(h[0], h[1]);
    uint_t pk1 = upk(h[2], h[3]);

    #pragma unroll 1
    for (int t = 0; t < T_OBS; t++) {
        float2 xv = obs[(size_t)t * BATCH + nb];
        lstm_step(Aobs, upk(xv.x, xv.y), lo, pk0, pk1, c, h, zacc);
    }

    // c_out (transpose-then-reshape): out[u*B + b] = h[b][u]
    #pragma unroll
    for (int j = 0; j < 4; j++)
        out[(size_t)(half * 4 + j) * BATCH + nb] = h[j];

    // pre phase: h carries over, c re-initialized
    float4 cv2 = c0p[nb * 2 + half];
    c[0] = cv2.x; c[1] = cv2.y; c[2] = cv2.z; c[3] = cv2.w;

    #pragma unroll 1
    for (int t = 0; t < T_PRE; t++) {
        float2 xv = pre[(size_t)t * BATCH + nb];
        lstm_step(Apre, upk(xv.x, xv.y), lo, pk0, pk1, c, h, zacc);
    }

    #pragma unroll
    for (int j = 0; j < 4; j++)
        out[(size_t)(8 + half * 4 + j) * BATCH + nb] = h[j];
}

extern "C" void kernel_launch(void* const* d_in, const int* in_sizes, int n_in,
                              void* d_out, int out_size, void* d_ws, size_t ws_size,
                              hipStream_t stream) {
    prep_weights<<<1, 128, 0, stream>>>(
        (const float*)d_in[5],  (const float*)d_in[6],
        (const float*)d_in[7],  (const float*)d_in[8],
        (const float*)d_in[9],  (const float*)d_in[10],
        (const float*)d_in[11], (const float*)d_in[12],
        (const float*)d_in[13], (const float*)d_in[14],
        (uint_t*)d_ws);

    lstm_encoder<<<BATCH / 128, 256, 0, stream>>>(
        (const float2*)d_in[0], (const float2*)d_in[1],
        (const float4*)d_in[2], (const float4*)d_in[3], (const float4*)d_in[4],
        (const uint4*)d_ws, (float*)d_out);
}